// Round 14
// baseline (73.428 us; speedup 1.0000x reference)
//
#include <hip/hip_runtime.h>
#include <math.h>

// Problem constants (match setup_inputs)
constexpr int N_NODES = 7650;
constexpr int F_FEAT  = 745;
constexpr int E_EDGES = 238162;
constexpr int NC1     = F_FEAT * 3;   // 2235
constexpr int PAD     = 128;          // ELL slots/row (max deg ~65 for random E/N=31)

// Workspace layout (float-word offsets), ~8.3 MB of ws
constexpr size_t OFF_CF    = 0;         // 16   jacobi triples
constexpr size_t OFF_BU    = 16;        // 9    b_j^T U1
constexpr size_t OFF_C1    = 128;       // 2235 (W1 @ U1)
constexpr size_t OFF_DEG   = 2432;      // 7650 float degree (Σ attr per row)
constexpr size_t OFF_CNT   = 10112;     // 7650 int ELL counts
constexpr size_t OFF_EPACK = 17792;     // 7650*128 int2 {col, attr|weight} -> 1976192
constexpr size_t OFF_B0    = 1976192;   // N*4 poly states (16B aligned)
constexpr size_t OFF_B1    = 2006912;
constexpr size_t OFF_B2    = 2037632;
constexpr size_t OFF_RPART = 2068352;   // 479*32 reduce partials

// r14: 8 -> 6 launches. scatter||xz re-merged (block-role split, keeping r13's
// shapes); deg_kernel deleted (deg via scatter atomics, disv() inline in spmm).
constexpr int BLD_THREADS = 512;
constexpr int SCT_BLOCKS  = (E_EDGES + BLD_THREADS - 1) / BLD_THREADS;  // 466, 1 edge/thread
constexpr int XZ_BLOCKS   = (N_NODES + 7) / 8;                          // 957, 1 row/wave
constexpr int BLD_BLOCKS  = SCT_BLOCKS + XZ_BLOCKS;                     // 1423

constexpr int SPMM_TPB  = 256;                               // 16 groups of 16 lanes
constexpr int SPMM_GRID = (N_NODES * 16 + SPMM_TPB - 1) / SPMM_TPB;   // 479

// ---------------- device helpers ----------------
__device__ __forceinline__ void jacobi_coefs(const float* __restrict__ alphas_raw,
                                             float* __restrict__ cf) {
    float al[4];
    #pragma unroll
    for (int i = 0; i < 4; ++i) al[i] = tanhf(alphas_raw[i]);
    const float a = 1.f, b = 1.f, l = -1.f, r = 1.f;
    float coef1 = (a - b) * 0.5f - (a + b + 2.f) * 0.5f * (l + r) / (r - l);
    float coef2 = (a + b + 2.f) / (r - l);
    cf[0] = al[0] * coef2;     // out = cf0*Ax - cf1*xm1 - cf2*xm2
    cf[1] = -al[0] * coef1;
    cf[2] = 0.f;
    for (int L = 2; L <= 3; ++L) {
        float Lf = (float)L;
        float coef_l     = 2.f * Lf * (Lf + a + b) * (2.f * Lf - 2.f + a + b);
        float coef_lm1_1 = (2.f * Lf + a + b - 1.f) * (2.f * Lf + a + b) * (2.f * Lf + a + b - 2.f);
        float coef_lm1_2 = (2.f * Lf + a + b - 1.f) * (a * a - b * b);
        float coef_lm2   = 2.f * (Lf - 1.f + a) * (Lf - 1.f + b) * (2.f * Lf + a + b);
        float tmp1   = al[L - 1] * (coef_lm1_1 / coef_l);
        float tmp2   = al[L - 1] * (coef_lm1_2 / coef_l);
        float tmp3   = al[L - 1] * al[L - 2] * (coef_lm2 / coef_l);
        int o = 3 * (L - 1);
        cf[o + 0] = tmp1 * (2.f / (r - l));
        cf[o + 1] = tmp1 * ((r + l) / (r - l)) + tmp2;
        cf[o + 2] = tmp3;
    }
}

__device__ __forceinline__ float disv(float dg) {
    return (dg > 0.f) ? 1.f / sqrtf(fmaxf(dg, 1e-12f)) : 0.f;
}

// ---------------- L1: init (zero deg/cnt + coef + bu + C1) ----------------
constexpr int INIT_BLOCKS = 205;
__global__ void init_kernel(const float* __restrict__ alphas_raw, const float* __restrict__ b1,
                            const float* __restrict__ b2, const float* __restrict__ b3,
                            const float* __restrict__ U1, const float* __restrict__ W1,
                            float* __restrict__ ws) {
    int b = blockIdx.x, t = threadIdx.x;
    if (b < 8) {                                     // zero deg + cnt
        float* deg = ws + OFF_DEG;
        int*   cnt = (int*)(ws + OFF_CNT);
        for (int i = b * 256 + t; i < N_NODES; i += 8 * 256) { deg[i] = 0.f; cnt[i] = 0; }
        return;
    }
    if (b == 8) {
        if (t == 0) jacobi_coefs(alphas_raw, ws + OFF_CF);
        return;
    }
    if (b < 18) {                                    // bu: 9 blocks, wave 0
        if (t >= 64) return;
        int o = b - 9, j = o / 3, s = o - j * 3;
        const float* bb = (j == 0) ? b1 : ((j == 1) ? b2 : b3);
        float acc = 0.f;
        for (int k = t; k < F_FEAT; k += 64) acc += bb[k] * U1[k * 3 + s];
        #pragma unroll
        for (int off = 32; off; off >>= 1) acc += __shfl_down(acc, off);
        if (t == 0) (ws + OFF_BU)[o] = acc;
        return;
    }
    // C1 = W1 @ U1: one wave per W1 row, 4 waves/block (256 threads)
    int f = (b - 18) * 4 + (t >> 6), lane = t & 63;
    if (f >= F_FEAT) return;
    const float* wr = W1 + (size_t)f * F_FEAT;
    float s0 = 0.f, s1 = 0.f, s2 = 0.f;
    for (int k = lane; k < F_FEAT; k += 64) {
        float wv = wr[k];
        s0 += wv * U1[k * 3 + 0];
        s1 += wv * U1[k * 3 + 1];
        s2 += wv * U1[k * 3 + 2];
    }
    #pragma unroll
    for (int off = 32; off; off >>= 1) {
        s0 += __shfl_down(s0, off);
        s1 += __shfl_down(s1, off);
        s2 += __shfl_down(s2, off);
    }
    if (lane == 0) {
        float* C1 = ws + OFF_C1;
        C1[f * 3] = s0; C1[f * 3 + 1] = s1; C1[f * 3 + 2] = s2;
    }
}

// ---------------- L2: ELL scatter + deg  ||  B0 = [X@C1 | 1] ----------------
__global__ __launch_bounds__(BLD_THREADS)
void build_kernel(const int* __restrict__ edge_index, const float* __restrict__ edge_attr,
                  const float* __restrict__ X, float* __restrict__ ws) {
    __shared__ float sC[NC1];
    const int t = threadIdx.x, b = blockIdx.x;
    if (b < SCT_BLOCKS) {
        int e = b * BLD_THREADS + t;
        if (e >= E_EDGES) return;
        const int* row = edge_index;
        const int* col = edge_index + E_EDGES;
        float* deg = ws + OFF_DEG;
        int*   cnt = (int*)(ws + OFF_CNT);
        int2*  epk = (int2*)(ws + OFF_EPACK);
        int r    = row[e];
        int c    = col[e];
        float av = edge_attr[e];
        atomicAdd(&deg[r], av);
        int p = atomicAdd(&cnt[r], 1);
        if (p < PAD) epk[r * PAD + p] = make_int2(c, __float_as_int(av));
        return;
    }
    // xz part: one row per wave
    const float* C1 = ws + OFF_C1;
    for (int i = t; i < NC1; i += BLD_THREADS) sC[i] = C1[i];
    __syncthreads();
    const int lane = t & 63;
    int rowi = (b - SCT_BLOCKS) * (BLD_THREADS / 64) + (t >> 6);
    if (rowi >= N_NODES) return;
    const float* xr = X + (size_t)rowi * F_FEAT;
    float s0 = 0.f, s1 = 0.f, s2 = 0.f;
    for (int k = lane; k < F_FEAT; k += 64) {
        float xv = xr[k];
        s0 += xv * sC[k * 3 + 0];
        s1 += xv * sC[k * 3 + 1];
        s2 += xv * sC[k * 3 + 2];
    }
    #pragma unroll
    for (int off = 32; off; off >>= 1) {
        s0 += __shfl_down(s0, off);
        s1 += __shfl_down(s1, off);
        s2 += __shfl_down(s2, off);
    }
    if (lane == 0) ((float4*)(ws + OFF_B0))[rowi] = make_float4(s0, s1, s2, 1.f);
}

// ---------------- L3: spmm1 (inline disv, fold dis[c] into packed w), B0 -> B1 ----------------
__global__ void spmm1_kernel(float* __restrict__ ws) {
    int gid = blockIdx.x * (SPMM_TPB >> 4) + (threadIdx.x >> 4);
    int sub = threadIdx.x & 15;
    if (gid >= N_NODES) return;
    const float* deg = ws + OFF_DEG;
    const int*   cnt = (const int*)(ws + OFF_CNT);
    int2*        epk = (int2*)(ws + OFF_EPACK);
    const float4* B0 = (const float4*)(ws + OFF_B0);
    float4*       B1 = (float4*)(ws + OFF_B1);
    const float* cf = ws + OFF_CF;

    int s = cnt[gid]; if (s > PAD) s = PAD;
    int base = gid * PAD;
    float ax = 0.f, ay = 0.f, az = 0.f, aw = 0.f;
    for (int j = sub; j < s; j += 16) {
        int2 pk = epk[base + j];
        int c = pk.x;
        float wv = __int_as_float(pk.y) * disv(deg[c]);
        epk[base + j] = make_int2(c, __float_as_int(wv));   // persist attr*dis[c]
        float4 v = B0[c];
        ax += wv * v.x; ay += wv * v.y; az += wv * v.z; aw += wv * v.w;
    }
    #pragma unroll
    for (int off = 8; off; off >>= 1) {
        ax += __shfl_xor(ax, off, 16); ay += __shfl_xor(ay, off, 16);
        az += __shfl_xor(az, off, 16); aw += __shfl_xor(aw, off, 16);
    }
    if (sub == 0) {
        float cA = cf[0] * disv(deg[gid]), cB = cf[1];
        float4 x1 = B0[gid];
        B1[gid] = make_float4(cA * ax - cB * x1.x, cA * ay - cB * x1.y,
                              cA * az - cB * x1.z, cA * aw - cB * x1.w);
    }
}

// ---------------- L4: spmm2, B1 -> B2 ----------------
__global__ void spmm2_kernel(float* __restrict__ ws) {
    int gid = blockIdx.x * (SPMM_TPB >> 4) + (threadIdx.x >> 4);
    int sub = threadIdx.x & 15;
    if (gid >= N_NODES) return;
    const float* deg = ws + OFF_DEG;
    const int*   cnt = (const int*)(ws + OFF_CNT);
    const int2*  epk = (const int2*)(ws + OFF_EPACK);
    const float4* B0 = (const float4*)(ws + OFF_B0);
    const float4* B1 = (const float4*)(ws + OFF_B1);
    float4*       B2 = (float4*)(ws + OFF_B2);
    const float* cf = ws + OFF_CF + 3;

    int s = cnt[gid]; if (s > PAD) s = PAD;
    int base = gid * PAD;
    float ax = 0.f, ay = 0.f, az = 0.f, aw = 0.f;
    for (int j = sub; j < s; j += 16) {
        int2 pk = epk[base + j];
        float wv = __int_as_float(pk.y);
        float4 v = B1[pk.x];
        ax += wv * v.x; ay += wv * v.y; az += wv * v.z; aw += wv * v.w;
    }
    #pragma unroll
    for (int off = 8; off; off >>= 1) {
        ax += __shfl_xor(ax, off, 16); ay += __shfl_xor(ay, off, 16);
        az += __shfl_xor(az, off, 16); aw += __shfl_xor(aw, off, 16);
    }
    if (sub == 0) {
        float cA = cf[0] * disv(deg[gid]), cB = cf[1], cC = cf[2];
        float4 x1 = B1[gid], x2 = B0[gid];
        B2[gid] = make_float4(cA * ax - cB * x1.x - cC * x2.x,
                              cA * ay - cB * x1.y - cC * x2.y,
                              cA * az - cB * x1.z - cC * x2.z,
                              cA * aw - cB * x1.w - cC * x2.w);
    }
}

// ---------------- L5: spmm3 (x3 in reg) + fused U0 reduce -> Rp ----------------
__global__ void spmm3_reduce_kernel(const float* __restrict__ U0, float* __restrict__ ws) {
    __shared__ float smem[544];
    const int t = threadIdx.x, b = blockIdx.x;
    int gid = b * (SPMM_TPB >> 4) + (t >> 4);
    int sub = t & 15;
    const float* deg = ws + OFF_DEG;
    const int*   cnt = (const int*)(ws + OFF_CNT);
    const int2*  epk = (const int2*)(ws + OFF_EPACK);
    const float4* B0 = (const float4*)(ws + OFF_B0);
    const float4* B1 = (const float4*)(ws + OFF_B1);
    const float4* B2 = (const float4*)(ws + OFF_B2);
    float* Rp = ws + OFF_RPART;
    const float* cf = ws + OFF_CF + 6;

    float4 racc = make_float4(0.f, 0.f, 0.f, 0.f);
    if (gid < N_NODES) {
        int s = cnt[gid]; if (s > PAD) s = PAD;
        int base = gid * PAD;
        float ax = 0.f, ay = 0.f, az = 0.f, aw = 0.f;
        for (int j = sub; j < s; j += 16) {
            int2 pk = epk[base + j];
            float wv = __int_as_float(pk.y);
            float4 v = B2[pk.x];
            ax += wv * v.x; ay += wv * v.y; az += wv * v.z; aw += wv * v.w;
        }
        #pragma unroll
        for (int off = 8; off; off >>= 1) {          // full butterfly: all lanes get sums
            ax += __shfl_xor(ax, off, 16); ay += __shfl_xor(ay, off, 16);
            az += __shfl_xor(az, off, 16); aw += __shfl_xor(aw, off, 16);
        }
        float cA = cf[0] * disv(deg[gid]), cB = cf[1], cC = cf[2];
        float4 x1 = B2[gid], x2 = B1[gid], x0 = B0[gid];
        float4 b3 = make_float4(cA * ax - cB * x1.x - cC * x2.x,
                                cA * ay - cB * x1.y - cC * x2.y,
                                cA * az - cB * x1.z - cC * x2.z,
                                cA * aw - cB * x1.w - cC * x2.w);
        if (sub < 8) {
            float u = U0[(size_t)gid * 8 + sub];
            racc.x = u * (x0.x + x1.x + x2.x + b3.x);
            racc.y = u * (x0.y + x1.y + x2.y + b3.y);
            racc.z = u * (x0.z + x1.z + x2.z + b3.z);
            racc.w = u * (x0.w + x1.w + x2.w + b3.w);
        }
    }
    // block reduce: 16 groups x 32 values -> Rp[b*32 + 0..31]
    int g = t >> 4;
    if (sub < 8) {
        smem[g * 32 + sub * 4 + 0] = racc.x;
        smem[g * 32 + sub * 4 + 1] = racc.y;
        smem[g * 32 + sub * 4 + 2] = racc.z;
        smem[g * 32 + sub * 4 + 3] = racc.w;
    }
    __syncthreads();
    if (t < 32) {
        float tot = 0.f;
        #pragma unroll
        for (int k = 0; k < 16; ++k) tot += smem[k * 32 + t];
        Rp[b * 32 + t] = tot;
    }
}

// ---------------- L6: final (1 block): sum Rp + PARALLEL TRL ----------------
__global__ void final_kernel(const float* __restrict__ U2, const float* __restrict__ core,
                             const float* __restrict__ U3, const float* __restrict__ trl_bias,
                             float* __restrict__ ws, float* __restrict__ out) {
    __shared__ float sCore[576];
    __shared__ float sU3[64];
    __shared__ float sU2[9];
    __shared__ float sBu[9];
    __shared__ float sR[32];
    __shared__ float sRst[72];
    __shared__ float sUvec[8];
    __shared__ float sO[8];
    __shared__ float sred[256];
    __shared__ float sBias;
    const int t = threadIdx.x;
    const float* Rp = ws + OFF_RPART;
    const float* bu = ws + OFF_BU;

    // stage small tensors coalesced into LDS
    for (int i = t; i < 576; i += 256) sCore[i] = core[i];
    if (t < 64) sU3[t] = U3[t];
    if (t >= 64 && t < 73) sU2[t - 64] = U2[t - 64];
    if (t >= 96 && t < 105) sBu[t - 96] = bu[t - 96];
    if (t == 128) sBias = trl_bias[0];

    // sum 479 partials (8 thread-groups of 32)
    float p = 0.f;
    for (int b2 = t >> 5; b2 < SPMM_GRID; b2 += 8) p += Rp[b2 * 32 + (t & 31)];
    sred[t] = p;
    __syncthreads();
    if (t < 32) {
        float tot = 0.f;
        #pragma unroll
        for (int k = 0; k < 8; ++k) tot += sred[k * 32 + t];
        sR[t] = tot;
    }
    __syncthreads();

    // 72-way parallel: rst[(rr,s,tt)] = sum_c M[c][rr][s] * U2[c][tt]
    if (t < 72) {
        int rr = t / 9, rem = t - rr * 9, s = rem / 3, tt = rem - s * 3;
        float q  = sR[rr * 4 + 3];
        float m0 = sR[rr * 4 + s] + q * sBu[s];
        float m1 = q * sBu[3 + s];
        float m2 = q * sBu[6 + s];
        sRst[t] = m0 * sU2[tt] + m1 * sU2[3 + tt] + m2 * sU2[6 + tt];
    }
    __syncthreads();

    // 8-way: uvec[u] = sum_k rst[k] * core[k][u]
    if (t < 8) {
        float acc = 0.f;
        #pragma unroll 8
        for (int k = 0; k < 72; ++k) acc += sRst[k] * sCore[k * 8 + t];
        sUvec[t] = acc;
    }
    __syncthreads();

    // 8-way: o[k] = bias + sum_u uvec[u] * U3[k][u]
    if (t < 8) {
        float acc = sBias;
        #pragma unroll
        for (int u = 0; u < 8; ++u) acc += sUvec[u] * sU3[t * 8 + u];
        sO[t] = acc;
    }
    __syncthreads();

    if (t == 0) {
        float mx = -1e30f;
        #pragma unroll
        for (int k = 0; k < 8; ++k) mx = fmaxf(mx, sO[k]);
        float se = 0.f;
        #pragma unroll
        for (int k = 0; k < 8; ++k) se += expf(sO[k] - mx);
        float lse = mx + logf(se);
        #pragma unroll
        for (int k = 0; k < 8; ++k) out[k] = sO[k] - lse;
    }
}

extern "C" void kernel_launch(void* const* d_in, const int* in_sizes, int n_in,
                              void* d_out, int out_size, void* d_ws, size_t ws_size,
                              hipStream_t stream) {
    const float* X          = (const float*)d_in[0];
    const int*   edge_index = (const int*)d_in[1];
    const float* edge_attr  = (const float*)d_in[2];
    const float* W1         = (const float*)d_in[3];
    const float* b1         = (const float*)d_in[4];
    const float* b2         = (const float*)d_in[6];
    const float* b3         = (const float*)d_in[8];
    const float* alphas_raw = (const float*)d_in[9];
    const float* core       = (const float*)d_in[10];
    const float* U0         = (const float*)d_in[11];
    const float* U1         = (const float*)d_in[12];
    const float* U2         = (const float*)d_in[13];
    const float* U3         = (const float*)d_in[14];
    const float* trl_bias   = (const float*)d_in[15];

    float* ws   = (float*)d_ws;
    float* outp = (float*)d_out;

    init_kernel<<<INIT_BLOCKS, 256, 0, stream>>>(alphas_raw, b1, b2, b3, U1, W1, ws);
    build_kernel<<<BLD_BLOCKS, BLD_THREADS, 0, stream>>>(edge_index, edge_attr, X, ws);
    spmm1_kernel<<<SPMM_GRID, SPMM_TPB, 0, stream>>>(ws);
    spmm2_kernel<<<SPMM_GRID, SPMM_TPB, 0, stream>>>(ws);
    spmm3_reduce_kernel<<<SPMM_GRID, SPMM_TPB, 0, stream>>>(U0, ws);
    final_kernel<<<1, 256, 0, stream>>>(U2, core, U3, trl_bias, ws, outp);
}

// Round 15
// 65.066 us; speedup vs baseline: 1.1285x; 1.1285x over previous
//
#include <hip/hip_runtime.h>
#include <math.h>

// Problem constants (match setup_inputs)
constexpr int N_NODES = 7650;
constexpr int F_FEAT  = 745;
constexpr int E_EDGES = 238162;
constexpr int NC1     = F_FEAT * 3;   // 2235
constexpr int PAD     = 128;          // ELL slots/row (max deg ~65 for random E/N=31)

// Workspace layout (float-word offsets), ~8.3 MB of ws
constexpr size_t OFF_CF    = 0;         // 16   jacobi triples
constexpr size_t OFF_BU    = 16;        // 9    b_j^T U1
constexpr size_t OFF_C1    = 128;       // 2235 (W1 @ U1)
constexpr size_t OFF_DIS   = 2432;      // 7650 dis = deg^{-1/2}
constexpr size_t OFF_CNT   = 10112;     // 7650 int ELL counts
constexpr size_t OFF_EPACK = 17792;     // 7650*128 int2 {col, attr|weight} -> 1976192
constexpr size_t OFF_B0    = 1976192;   // N*4 poly states (16B aligned)
constexpr size_t OFF_B1    = 2006912;
constexpr size_t OFF_B2    = 2037632;
constexpr size_t OFF_RPART = 2068352;   // 479*32 reduce partials

// r15: exact r13 bodies (65.6 us best); single change = deg+xz merged into one
// block-role kernel after scatter (8 -> 7 launches). NO atomics re-added
// (r14 lesson: deg atomic + per-slot rsqrt cost ~8us; launch gaps are cheap).
constexpr int SCT_THREADS = 512;
constexpr int SCT_BLOCKS  = (E_EDGES + SCT_THREADS - 1) / SCT_THREADS;  // 466, 1 edge/thread

constexpr int XD_THREADS  = 512;
constexpr int DEG_BLOCKS  = (N_NODES + 31) / 32;                        // 240 (32 rows/block)
constexpr int XZ_BLOCKS   = (N_NODES + 7) / 8;                          // 957 (8 rows/block)
constexpr int XD_BLOCKS   = DEG_BLOCKS + XZ_BLOCKS;                     // 1197

constexpr int SPMM_TPB  = 256;                               // 16 groups of 16 lanes
constexpr int SPMM_GRID = (N_NODES * 16 + SPMM_TPB - 1) / SPMM_TPB;   // 479

// ---------------- device helpers ----------------
__device__ __forceinline__ void jacobi_coefs(const float* __restrict__ alphas_raw,
                                             float* __restrict__ cf) {
    float al[4];
    #pragma unroll
    for (int i = 0; i < 4; ++i) al[i] = tanhf(alphas_raw[i]);
    const float a = 1.f, b = 1.f, l = -1.f, r = 1.f;
    float coef1 = (a - b) * 0.5f - (a + b + 2.f) * 0.5f * (l + r) / (r - l);
    float coef2 = (a + b + 2.f) / (r - l);
    cf[0] = al[0] * coef2;     // out = cf0*Ax - cf1*xm1 - cf2*xm2
    cf[1] = -al[0] * coef1;
    cf[2] = 0.f;
    for (int L = 2; L <= 3; ++L) {
        float Lf = (float)L;
        float coef_l     = 2.f * Lf * (Lf + a + b) * (2.f * Lf - 2.f + a + b);
        float coef_lm1_1 = (2.f * Lf + a + b - 1.f) * (2.f * Lf + a + b) * (2.f * Lf + a + b - 2.f);
        float coef_lm1_2 = (2.f * Lf + a + b - 1.f) * (a * a - b * b);
        float coef_lm2   = 2.f * (Lf - 1.f + a) * (Lf - 1.f + b) * (2.f * Lf + a + b);
        float tmp1   = al[L - 1] * (coef_lm1_1 / coef_l);
        float tmp2   = al[L - 1] * (coef_lm1_2 / coef_l);
        float tmp3   = al[L - 1] * al[L - 2] * (coef_lm2 / coef_l);
        int o = 3 * (L - 1);
        cf[o + 0] = tmp1 * (2.f / (r - l));
        cf[o + 1] = tmp1 * ((r + l) / (r - l)) + tmp2;
        cf[o + 2] = tmp3;
    }
}

__device__ __forceinline__ float disv(float dg) {
    return (dg > 0.f) ? 1.f / sqrtf(fmaxf(dg, 1e-12f)) : 0.f;
}

// ---------------- L1: init (zero cnt + coef + bu + C1) ----------------
constexpr int INIT_BLOCKS = 205;
__global__ void init_kernel(const float* __restrict__ alphas_raw, const float* __restrict__ b1,
                            const float* __restrict__ b2, const float* __restrict__ b3,
                            const float* __restrict__ U1, const float* __restrict__ W1,
                            float* __restrict__ ws) {
    int b = blockIdx.x, t = threadIdx.x;
    if (b < 8) {                                     // zero cnt
        int* cnt = (int*)(ws + OFF_CNT);
        for (int i = b * 256 + t; i < N_NODES; i += 8 * 256) cnt[i] = 0;
        return;
    }
    if (b == 8) {
        if (t == 0) jacobi_coefs(alphas_raw, ws + OFF_CF);
        return;
    }
    if (b < 18) {                                    // bu: 9 blocks, wave 0
        if (t >= 64) return;
        int o = b - 9, j = o / 3, s = o - j * 3;
        const float* bb = (j == 0) ? b1 : ((j == 1) ? b2 : b3);
        float acc = 0.f;
        for (int k = t; k < F_FEAT; k += 64) acc += bb[k] * U1[k * 3 + s];
        #pragma unroll
        for (int off = 32; off; off >>= 1) acc += __shfl_down(acc, off);
        if (t == 0) (ws + OFF_BU)[o] = acc;
        return;
    }
    // C1 = W1 @ U1: one wave per W1 row, 4 waves/block (256 threads)
    int f = (b - 18) * 4 + (t >> 6), lane = t & 63;
    if (f >= F_FEAT) return;
    const float* wr = W1 + (size_t)f * F_FEAT;
    float s0 = 0.f, s1 = 0.f, s2 = 0.f;
    for (int k = lane; k < F_FEAT; k += 64) {
        float wv = wr[k];
        s0 += wv * U1[k * 3 + 0];
        s1 += wv * U1[k * 3 + 1];
        s2 += wv * U1[k * 3 + 2];
    }
    #pragma unroll
    for (int off = 32; off; off >>= 1) {
        s0 += __shfl_down(s0, off);
        s1 += __shfl_down(s1, off);
        s2 += __shfl_down(s2, off);
    }
    if (lane == 0) {
        float* C1 = ws + OFF_C1;
        C1[f * 3] = s0; C1[f * 3 + 1] = s1; C1[f * 3 + 2] = s2;
    }
}

// ---------------- L2: ELL scatter (one edge/thread; only the cursor atomic) ----------------
__global__ __launch_bounds__(SCT_THREADS)
void scatter_kernel(const int* __restrict__ edge_index, const float* __restrict__ edge_attr,
                    float* __restrict__ ws) {
    int e = blockIdx.x * SCT_THREADS + threadIdx.x;
    if (e >= E_EDGES) return;
    const int* row = edge_index;
    const int* col = edge_index + E_EDGES;
    int*  cnt = (int*)(ws + OFF_CNT);
    int2* epk = (int2*)(ws + OFF_EPACK);
    int r    = row[e];
    int c    = col[e];
    float av = edge_attr[e];
    int p = atomicAdd(&cnt[r], 1);
    if (p < PAD) epk[r * PAD + p] = make_int2(c, __float_as_int(av));
}

// ---------------- L3: dis from slots (blocks<DEG_BLOCKS)  ||  B0 = [X@C1 | 1] ----------------
__global__ __launch_bounds__(XD_THREADS)
void xzdeg_kernel(const float* __restrict__ X, float* __restrict__ ws) {
    __shared__ float sC[NC1];
    const int t = threadIdx.x, b = blockIdx.x;
    if (b < DEG_BLOCKS) {
        // deg role: 32 rows/block, 16 lanes/row
        int gid = b * 32 + (t >> 4);
        int sub = t & 15;
        if (gid >= N_NODES) return;
        const int*  cnt = (const int*)(ws + OFF_CNT);
        const int2* epk = (const int2*)(ws + OFF_EPACK);
        int s = cnt[gid]; if (s > PAD) s = PAD;
        int base = gid * PAD;
        float dg = 0.f;
        for (int j = sub; j < s; j += 16) dg += __int_as_float(epk[base + j].y);
        #pragma unroll
        for (int off = 8; off; off >>= 1) dg += __shfl_xor(dg, off, 16);
        if (sub == 0) (ws + OFF_DIS)[gid] = disv(dg);
        return;
    }
    // xz role: one row per wave
    const float* C1 = ws + OFF_C1;
    for (int i = t; i < NC1; i += XD_THREADS) sC[i] = C1[i];
    __syncthreads();
    const int lane = t & 63;
    int rowi = (b - DEG_BLOCKS) * (XD_THREADS / 64) + (t >> 6);
    if (rowi >= N_NODES) return;
    const float* xr = X + (size_t)rowi * F_FEAT;
    float s0 = 0.f, s1 = 0.f, s2 = 0.f;
    for (int k = lane; k < F_FEAT; k += 64) {
        float xv = xr[k];
        s0 += xv * sC[k * 3 + 0];
        s1 += xv * sC[k * 3 + 1];
        s2 += xv * sC[k * 3 + 2];
    }
    #pragma unroll
    for (int off = 32; off; off >>= 1) {
        s0 += __shfl_down(s0, off);
        s1 += __shfl_down(s1, off);
        s2 += __shfl_down(s2, off);
    }
    if (lane == 0) ((float4*)(ws + OFF_B0))[rowi] = make_float4(s0, s1, s2, 1.f);
}

// ---------------- L4: spmm1 (fold dis[c] into packed w), B0 -> B1 ----------------
__global__ void spmm1_kernel(float* __restrict__ ws) {
    int gid = blockIdx.x * (SPMM_TPB >> 4) + (threadIdx.x >> 4);
    int sub = threadIdx.x & 15;
    if (gid >= N_NODES) return;
    const float* dis = ws + OFF_DIS;
    const int*   cnt = (const int*)(ws + OFF_CNT);
    int2*        epk = (int2*)(ws + OFF_EPACK);
    const float4* B0 = (const float4*)(ws + OFF_B0);
    float4*       B1 = (float4*)(ws + OFF_B1);
    const float* cf = ws + OFF_CF;

    int s = cnt[gid]; if (s > PAD) s = PAD;
    int base = gid * PAD;
    float ax = 0.f, ay = 0.f, az = 0.f, aw = 0.f;
    for (int j = sub; j < s; j += 16) {
        int2 pk = epk[base + j];
        int c = pk.x;
        float wv = __int_as_float(pk.y) * dis[c];
        epk[base + j] = make_int2(c, __float_as_int(wv));   // persist attr*dis[c]
        float4 v = B0[c];
        ax += wv * v.x; ay += wv * v.y; az += wv * v.z; aw += wv * v.w;
    }
    #pragma unroll
    for (int off = 8; off; off >>= 1) {
        ax += __shfl_xor(ax, off, 16); ay += __shfl_xor(ay, off, 16);
        az += __shfl_xor(az, off, 16); aw += __shfl_xor(aw, off, 16);
    }
    if (sub == 0) {
        float cA = cf[0] * dis[gid], cB = cf[1];
        float4 x1 = B0[gid];
        B1[gid] = make_float4(cA * ax - cB * x1.x, cA * ay - cB * x1.y,
                              cA * az - cB * x1.z, cA * aw - cB * x1.w);
    }
}

// ---------------- L5: spmm2, B1 -> B2 ----------------
__global__ void spmm2_kernel(float* __restrict__ ws) {
    int gid = blockIdx.x * (SPMM_TPB >> 4) + (threadIdx.x >> 4);
    int sub = threadIdx.x & 15;
    if (gid >= N_NODES) return;
    const float* dis = ws + OFF_DIS;
    const int*   cnt = (const int*)(ws + OFF_CNT);
    const int2*  epk = (const int2*)(ws + OFF_EPACK);
    const float4* B0 = (const float4*)(ws + OFF_B0);
    const float4* B1 = (const float4*)(ws + OFF_B1);
    float4*       B2 = (float4*)(ws + OFF_B2);
    const float* cf = ws + OFF_CF + 3;

    int s = cnt[gid]; if (s > PAD) s = PAD;
    int base = gid * PAD;
    float ax = 0.f, ay = 0.f, az = 0.f, aw = 0.f;
    for (int j = sub; j < s; j += 16) {
        int2 pk = epk[base + j];
        float wv = __int_as_float(pk.y);
        float4 v = B1[pk.x];
        ax += wv * v.x; ay += wv * v.y; az += wv * v.z; aw += wv * v.w;
    }
    #pragma unroll
    for (int off = 8; off; off >>= 1) {
        ax += __shfl_xor(ax, off, 16); ay += __shfl_xor(ay, off, 16);
        az += __shfl_xor(az, off, 16); aw += __shfl_xor(aw, off, 16);
    }
    if (sub == 0) {
        float cA = cf[0] * dis[gid], cB = cf[1], cC = cf[2];
        float4 x1 = B1[gid], x2 = B0[gid];
        B2[gid] = make_float4(cA * ax - cB * x1.x - cC * x2.x,
                              cA * ay - cB * x1.y - cC * x2.y,
                              cA * az - cB * x1.z - cC * x2.z,
                              cA * aw - cB * x1.w - cC * x2.w);
    }
}

// ---------------- L6: spmm3 (x3 in reg) + fused U0 reduce -> Rp ----------------
__global__ void spmm3_reduce_kernel(const float* __restrict__ U0, float* __restrict__ ws) {
    __shared__ float smem[544];
    const int t = threadIdx.x, b = blockIdx.x;
    int gid = b * (SPMM_TPB >> 4) + (t >> 4);
    int sub = t & 15;
    const float* dis = ws + OFF_DIS;
    const int*   cnt = (const int*)(ws + OFF_CNT);
    const int2*  epk = (const int2*)(ws + OFF_EPACK);
    const float4* B0 = (const float4*)(ws + OFF_B0);
    const float4* B1 = (const float4*)(ws + OFF_B1);
    const float4* B2 = (const float4*)(ws + OFF_B2);
    float* Rp = ws + OFF_RPART;
    const float* cf = ws + OFF_CF + 6;

    float4 racc = make_float4(0.f, 0.f, 0.f, 0.f);
    if (gid < N_NODES) {
        int s = cnt[gid]; if (s > PAD) s = PAD;
        int base = gid * PAD;
        float ax = 0.f, ay = 0.f, az = 0.f, aw = 0.f;
        for (int j = sub; j < s; j += 16) {
            int2 pk = epk[base + j];
            float wv = __int_as_float(pk.y);
            float4 v = B2[pk.x];
            ax += wv * v.x; ay += wv * v.y; az += wv * v.z; aw += wv * v.w;
        }
        #pragma unroll
        for (int off = 8; off; off >>= 1) {          // full butterfly: all lanes get sums
            ax += __shfl_xor(ax, off, 16); ay += __shfl_xor(ay, off, 16);
            az += __shfl_xor(az, off, 16); aw += __shfl_xor(aw, off, 16);
        }
        float cA = cf[0] * dis[gid], cB = cf[1], cC = cf[2];
        float4 x1 = B2[gid], x2 = B1[gid], x0 = B0[gid];
        float4 b3 = make_float4(cA * ax - cB * x1.x - cC * x2.x,
                                cA * ay - cB * x1.y - cC * x2.y,
                                cA * az - cB * x1.z - cC * x2.z,
                                cA * aw - cB * x1.w - cC * x2.w);
        if (sub < 8) {
            float u = U0[(size_t)gid * 8 + sub];
            racc.x = u * (x0.x + x1.x + x2.x + b3.x);
            racc.y = u * (x0.y + x1.y + x2.y + b3.y);
            racc.z = u * (x0.z + x1.z + x2.z + b3.z);
            racc.w = u * (x0.w + x1.w + x2.w + b3.w);
        }
    }
    // block reduce: 16 groups x 32 values -> Rp[b*32 + 0..31]
    int g = t >> 4;
    if (sub < 8) {
        smem[g * 32 + sub * 4 + 0] = racc.x;
        smem[g * 32 + sub * 4 + 1] = racc.y;
        smem[g * 32 + sub * 4 + 2] = racc.z;
        smem[g * 32 + sub * 4 + 3] = racc.w;
    }
    __syncthreads();
    if (t < 32) {
        float tot = 0.f;
        #pragma unroll
        for (int k = 0; k < 16; ++k) tot += smem[k * 32 + t];
        Rp[b * 32 + t] = tot;
    }
}

// ---------------- L7: final (1 block): sum Rp + PARALLEL TRL ----------------
__global__ void final_kernel(const float* __restrict__ U2, const float* __restrict__ core,
                             const float* __restrict__ U3, const float* __restrict__ trl_bias,
                             float* __restrict__ ws, float* __restrict__ out) {
    __shared__ float sCore[576];
    __shared__ float sU3[64];
    __shared__ float sU2[9];
    __shared__ float sBu[9];
    __shared__ float sR[32];
    __shared__ float sRst[72];
    __shared__ float sUvec[8];
    __shared__ float sO[8];
    __shared__ float sred[256];
    __shared__ float sBias;
    const int t = threadIdx.x;
    const float* Rp = ws + OFF_RPART;
    const float* bu = ws + OFF_BU;

    // stage small tensors coalesced into LDS
    for (int i = t; i < 576; i += 256) sCore[i] = core[i];
    if (t < 64) sU3[t] = U3[t];
    if (t >= 64 && t < 73) sU2[t - 64] = U2[t - 64];
    if (t >= 96 && t < 105) sBu[t - 96] = bu[t - 96];
    if (t == 128) sBias = trl_bias[0];

    // sum 479 partials (8 thread-groups of 32)
    float p = 0.f;
    for (int b2 = t >> 5; b2 < SPMM_GRID; b2 += 8) p += Rp[b2 * 32 + (t & 31)];
    sred[t] = p;
    __syncthreads();
    if (t < 32) {
        float tot = 0.f;
        #pragma unroll
        for (int k = 0; k < 8; ++k) tot += sred[k * 32 + t];
        sR[t] = tot;
    }
    __syncthreads();

    // 72-way parallel: rst[(rr,s,tt)] = sum_c M[c][rr][s] * U2[c][tt]
    if (t < 72) {
        int rr = t / 9, rem = t - rr * 9, s = rem / 3, tt = rem - s * 3;
        float q  = sR[rr * 4 + 3];
        float m0 = sR[rr * 4 + s] + q * sBu[s];
        float m1 = q * sBu[3 + s];
        float m2 = q * sBu[6 + s];
        sRst[t] = m0 * sU2[tt] + m1 * sU2[3 + tt] + m2 * sU2[6 + tt];
    }
    __syncthreads();

    // 8-way: uvec[u] = sum_k rst[k] * core[k][u]
    if (t < 8) {
        float acc = 0.f;
        #pragma unroll 8
        for (int k = 0; k < 72; ++k) acc += sRst[k] * sCore[k * 8 + t];
        sUvec[t] = acc;
    }
    __syncthreads();

    // 8-way: o[k] = bias + sum_u uvec[u] * U3[k][u]
    if (t < 8) {
        float acc = sBias;
        #pragma unroll
        for (int u = 0; u < 8; ++u) acc += sUvec[u] * sU3[t * 8 + u];
        sO[t] = acc;
    }
    __syncthreads();

    if (t == 0) {
        float mx = -1e30f;
        #pragma unroll
        for (int k = 0; k < 8; ++k) mx = fmaxf(mx, sO[k]);
        float se = 0.f;
        #pragma unroll
        for (int k = 0; k < 8; ++k) se += expf(sO[k] - mx);
        float lse = mx + logf(se);
        #pragma unroll
        for (int k = 0; k < 8; ++k) out[k] = sO[k] - lse;
    }
}

extern "C" void kernel_launch(void* const* d_in, const int* in_sizes, int n_in,
                              void* d_out, int out_size, void* d_ws, size_t ws_size,
                              hipStream_t stream) {
    const float* X          = (const float*)d_in[0];
    const int*   edge_index = (const int*)d_in[1];
    const float* edge_attr  = (const float*)d_in[2];
    const float* W1         = (const float*)d_in[3];
    const float* b1         = (const float*)d_in[4];
    const float* b2         = (const float*)d_in[6];
    const float* b3         = (const float*)d_in[8];
    const float* alphas_raw = (const float*)d_in[9];
    const float* core       = (const float*)d_in[10];
    const float* U0         = (const float*)d_in[11];
    const float* U1         = (const float*)d_in[12];
    const float* U2         = (const float*)d_in[13];
    const float* U3         = (const float*)d_in[14];
    const float* trl_bias   = (const float*)d_in[15];

    float* ws   = (float*)d_ws;
    float* outp = (float*)d_out;

    init_kernel<<<INIT_BLOCKS, 256, 0, stream>>>(alphas_raw, b1, b2, b3, U1, W1, ws);
    scatter_kernel<<<SCT_BLOCKS, SCT_THREADS, 0, stream>>>(edge_index, edge_attr, ws);
    xzdeg_kernel<<<XD_BLOCKS, XD_THREADS, 0, stream>>>(X, ws);
    spmm1_kernel<<<SPMM_GRID, SPMM_TPB, 0, stream>>>(ws);
    spmm2_kernel<<<SPMM_GRID, SPMM_TPB, 0, stream>>>(ws);
    spmm3_reduce_kernel<<<SPMM_GRID, SPMM_TPB, 0, stream>>>(U0, ws);
    final_kernel<<<1, 256, 0, stream>>>(U2, core, U3, trl_bias, ws, outp);
}